// Round 9
// baseline (282.244 us; speedup 1.0000x reference)
//
#include <hip/hip_runtime.h>
#include <hip/hip_fp16.h>

#define EMB_D 64
#define SB 1024     // scan block size
#define SPAN 128    // nodes per group (pow2: group = dst>>7, local = dst&127)
#define MAXG 1024   // max groups for LDS arrays
#define NCHUNK2 512 // edge chunks
#define CHMAX 4096  // max edges per chunk for LDS record buffer (32 KB)
#define TILE 4096   // gather tile (records)
#define SLICE_SH 14 // src-slice: 16384 rows = 2 MB of emb16 per slice
#define MAXS 8      // max slices (N < 131072)
#define SKEYBINS (MAXS * SPAN)
#define CAST_BLOCKS 256

// ===========================================================================
// Tier A9: slice-phased gather, MLP-restored.
//   A1 : fused fp16 cast + per-chunk group histogram (LDS atomics)
//   scan: 3-phase over [G][NCHUNK2] -> per-(chunk,group) global bases
//   PS : per-chunk LDS counting sort -> stream8 (group-contiguous)
//   GS : gather_sliced v2: 8-LANE crews (full 128B row via uint4/lane),
//        2 nodes/crew, the two node-streams walked INTERLEAVED 2-deep
//        -> 32 rows in flight/wave (2x R6). launch_bounds(512,8) caps
//        VGPR<=64 -> 4 blk/CU -> all 554 blocks co-resident, so the
//        soft inter-slice barrier (perf-only, bounded spin) is cheap.
// Tier A6 gather_fused kept for S>MAXS. Tier C: atomic scatter.
// R4: LDS-atomic accumulate ~100x too slow. R6: gather L2-miss-bound.
// R7: unsynced slice phasing useless (drift). R8: SYNCED phasing drops
//     FETCH 137->43.5 MB (proven L2-resident) but 16-lane crews shattered
//     MLP (bins of 2.8 recs, VALUBusy 12%) -> 133us. Fix = this kernel.
// ===========================================================================

__device__ __forceinline__ float h15_to_float(unsigned int bits) {
    return __half2float(__ushort_as_half((unsigned short)bits));
}

__device__ __forceinline__ uint4 rowld(const char* base, unsigned int pk,
                                       unsigned int qlo) {
    return *reinterpret_cast<const uint4*>(base + ((pk >> 15) * 128u + qlo));
}

__device__ __forceinline__ void fma8(float4& a, float4& b, uint4 r, float wt) {
    float2 x01 = __half22float2(*reinterpret_cast<__half2*>(&r.x));
    float2 x23 = __half22float2(*reinterpret_cast<__half2*>(&r.y));
    float2 x45 = __half22float2(*reinterpret_cast<__half2*>(&r.z));
    float2 x67 = __half22float2(*reinterpret_cast<__half2*>(&r.w));
    a.x = fmaf(x01.x, wt, a.x); a.y = fmaf(x01.y, wt, a.y);
    a.z = fmaf(x23.x, wt, a.z); a.w = fmaf(x23.y, wt, a.w);
    b.x = fmaf(x45.x, wt, b.x); b.y = fmaf(x45.y, wt, b.y);
    b.z = fmaf(x67.x, wt, b.z); b.w = fmaf(x67.y, wt, b.w);
}

// --- A1: fused cast + chunked group histogram (no global atomics) ---------
__global__ void a1_cast_hist(const float2* __restrict__ embin,
                             __half2* __restrict__ emb16, int n2,
                             const int* __restrict__ dst,
                             int* __restrict__ cntT,   // [G][NCHUNK2]
                             int E, int G, int chunk) {
    if (blockIdx.x < CAST_BLOCKS) {
        int i = blockIdx.x * blockDim.x + threadIdx.x;
        int st = CAST_BLOCKS * blockDim.x;
        for (; i < n2; i += st)
            emb16[i] = __float22half2_rn(embin[i]);
    } else {
        __shared__ int bins[MAXG];
        int hb = blockIdx.x - CAST_BLOCKS;
        for (int g = threadIdx.x; g < G; g += blockDim.x) bins[g] = 0;
        __syncthreads();
        int beg = hb * chunk;
        int end = min(beg + chunk, E);
        for (int i = beg + threadIdx.x; i < end; i += blockDim.x)
            atomicAdd(&bins[dst[i] >> 7], 1);
        __syncthreads();
        for (int g = threadIdx.x; g < G; g += blockDim.x)
            cntT[g * NCHUNK2 + hb] = bins[g];
    }
}

// --- generic 3-phase exclusive scan ---------------------------------------
__global__ void scan_reduceB(const int* __restrict__ counts,
                             int* __restrict__ partial, int M) {
    __shared__ int wsum[16];
    const int tid = threadIdx.x, lane = tid & 63, wid = tid >> 6;
    int i = blockIdx.x * SB + tid;
    int v = (i < M) ? counts[i] : 0;
    #pragma unroll
    for (int off = 32; off > 0; off >>= 1)
        v += __shfl_xor(v, off, 64);
    if (lane == 0) wsum[wid] = v;
    __syncthreads();
    if (tid == 0) {
        int s = 0;
        #pragma unroll
        for (int k = 0; k < 16; ++k) s += wsum[k];
        partial[blockIdx.x] = s;
    }
}

__global__ void scan_partials(const int* __restrict__ partial,
                              int* __restrict__ blockoff,
                              int* __restrict__ offsets, int numB, int M) {
    __shared__ int wsum[16];
    __shared__ int wpre[16];
    __shared__ int carry;
    const int tid = threadIdx.x, lane = tid & 63, wid = tid >> 6;
    if (tid == 0) carry = 0;
    const int nPass = (numB + SB - 1) / SB;
    for (int p = 0; p < nPass; ++p) {
        __syncthreads();
        int base = carry;
        int idx = p * SB + tid;
        int v = (idx < numB) ? partial[idx] : 0;
        int x = v;
        #pragma unroll
        for (int off = 1; off < 64; off <<= 1) {
            int t = __shfl_up(x, off, 64);
            if (lane >= off) x += t;
        }
        if (lane == 63) wsum[wid] = x;
        __syncthreads();
        if (wid == 0) {
            int s = (lane < 16) ? wsum[lane] : 0;
            #pragma unroll
            for (int off = 1; off < 16; off <<= 1) {
                int t = __shfl_up(s, off, 64);
                if (lane >= off) s += t;
            }
            if (lane < 16) wpre[lane] = s;
        }
        __syncthreads();
        int excl = base + ((wid > 0) ? wpre[wid - 1] : 0) + (x - v);
        if (idx < numB) blockoff[idx] = excl;
        __syncthreads();
        if (tid == 0) carry = base + wpre[15];
    }
    __syncthreads();
    if (tid == 0) offsets[M] = carry;   // grand total = E
}

__global__ void scan_applyB(const int* __restrict__ counts,
                            const int* __restrict__ blockoff,
                            int* __restrict__ offsets, int M) {
    __shared__ int wsum[16];
    __shared__ int wpre[16];
    const int tid = threadIdx.x, lane = tid & 63, wid = tid >> 6;
    int i = blockIdx.x * SB + tid;
    int v = (i < M) ? counts[i] : 0;
    int x = v;
    #pragma unroll
    for (int off = 1; off < 64; off <<= 1) {
        int t = __shfl_up(x, off, 64);
        if (lane >= off) x += t;
    }
    if (lane == 63) wsum[wid] = x;
    __syncthreads();
    if (wid == 0) {
        int s = (lane < 16) ? wsum[lane] : 0;
        #pragma unroll
        for (int off = 1; off < 16; off <<= 1) {
            int t = __shfl_up(s, off, 64);
            if (lane >= off) s += t;
        }
        if (lane < 16) wpre[lane] = s;
    }
    __syncthreads();
    int excl = blockoff[blockIdx.x] + ((wid > 0) ? wpre[wid - 1] : 0) + (x - v);
    if (i < M) offsets[i] = excl;
}

// --- PS: per-chunk LDS counting sort + linear coalesced drain (512 thr) ---
__global__ __launch_bounds__(512) void partition_sort(
        const int* __restrict__ src,
        const int* __restrict__ dst,
        const float* __restrict__ w,
        const int* __restrict__ cntT,    // [G][NCHUNK2]
        const int* __restrict__ scanT,   // [G*NCHUNK2+1]
        uint2* __restrict__ stream8,     // [E]
        int E, int G, int chunk) {
    __shared__ uint2 recs[CHMAX];        // 32 KB
    __shared__ int cur[MAXG];
    __shared__ int delta[MAXG];
    __shared__ int wtot[8];

    const int tid = threadIdx.x, lane = tid & 63, wv = tid >> 6;
    const int b = blockIdx.x;
    const int beg = b * chunk;
    const int end = min(beg + chunk, E);
    const int n = end - beg;

    const int K = (G + 511) >> 9;        // <= 2
    int vals[2];
    int acc = 0;
    #pragma unroll
    for (int k = 0; k < 2; ++k) {
        int g = tid * K + k;
        int c = (k < K && g < G) ? cntT[g * NCHUNK2 + b] : 0;
        vals[k] = c;
        acc += c;
    }
    int x = acc;
    #pragma unroll
    for (int off = 1; off < 64; off <<= 1) {
        int t = __shfl_up(x, off, 64);
        if (lane >= off) x += t;
    }
    if (lane == 63) wtot[wv] = x;
    __syncthreads();
    int woff = 0;
    #pragma unroll
    for (int k2 = 0; k2 < 8; ++k2)
        woff += (k2 < wv) ? wtot[k2] : 0;
    int run = woff + x - acc;
    #pragma unroll
    for (int k = 0; k < 2; ++k) {
        int g = tid * K + k;
        if (k < K && g < G) {
            cur[g] = run;
            delta[g] = scanT[g * NCHUNK2 + b] - run;
            run += vals[k];
        }
    }
    __syncthreads();

    for (int i = beg + tid; i < end; i += 512) {
        int d = dst[i];
        unsigned int wb = __half_as_ushort(__float2half_rn(w[i]));
        unsigned int pk = ((unsigned int)src[i] << 15) | (wb & 0x7FFFu);
        int g = d >> 7;
        int j = atomicAdd(&cur[g], 1);
        recs[j] = make_uint2(pk, (unsigned int)(d & (SPAN - 1)) |
                                 ((unsigned int)g << 7));
    }
    __syncthreads();

    for (int j = tid; j < n; j += 512) {
        uint2 r = recs[j];
        int g = (int)(r.y >> 7);
        stream8[delta[g] + j] = make_uint2(r.x, r.y & (SPAN - 1u));
    }
}

// --- helpers for gather_sliced --------------------------------------------
__device__ __forceinline__ void bin_scan(int* hcnt, int* nstart, int* cur,
                                         int* wtot, int NB) {
    const int tid = threadIdx.x, lane = tid & 63, wv = tid >> 6;
    int b0 = tid << 1, b1 = b0 + 1;
    int v0 = (b0 < NB) ? hcnt[b0] : 0;
    int v1 = (b1 < NB) ? hcnt[b1] : 0;
    int p = v0 + v1;
    int x = p;
    #pragma unroll
    for (int off = 1; off < 64; off <<= 1) {
        int t = __shfl_up(x, off, 64);
        if (lane >= off) x += t;
    }
    if (lane == 63) wtot[wv] = x;
    __syncthreads();
    int woff = 0;
    #pragma unroll
    for (int k = 0; k < 8; ++k) woff += (k < wv) ? wtot[k] : 0;
    int excl = woff + x - p;
    if (b0 < NB) { nstart[b0] = excl; cur[b0] = excl; }
    if (b1 < NB) { nstart[b1] = excl + v0; cur[b1] = excl + v0; }
    __syncthreads();
}

// soft grid barrier: perf hint only; bounded spin -> never deadlocks.
// cap ~128 * 0.43us ~ 55us worst case per barrier; normal wait: few us.
__device__ __forceinline__ void soft_grid_sync(int* bar, int phase, int nblk) {
    __syncthreads();
    if (threadIdx.x == 0) {
        int want = nblk * (phase + 1);
        int got = atomicAdd(bar, 1) + 1;
        int spins = 0;
        while (got < want && spins < 128) {
            __builtin_amdgcn_s_sleep(16);
            got = __hip_atomic_load(bar, __ATOMIC_RELAXED,
                                    __HIP_MEMORY_SCOPE_AGENT);
            ++spins;
        }
    }
    __syncthreads();
}

// --- GS v2: slice-phased gather, 8-lane crews, interleaved 2-node walk ----
// Crew = 8 lanes (lane ql covers dims [8*ql, 8*ql+8) via one uint4 = full
// 128B row per crew). Crew c owns nodes {c, c+64}. Per slice, the two
// node-streams are walked interleaved, each 2-deep -> 4 rows in flight
// per lane. launch_bounds(512,8): VGPR<=64 -> 4 blk/CU -> all co-resident.
__global__ __launch_bounds__(512, 8) void gather_sliced(
        const char* __restrict__ emb16b,      // row v at byte v*128
        const uint2* __restrict__ stream8,    // [E] {pk, dl}
        const int* __restrict__ scanT,        // [G*NCHUNK2+1]
        float* __restrict__ out, int N, int S, int* bar) {
    __shared__ unsigned int srt[TILE];        // 16 KB
    __shared__ int hcnt[SKEYBINS];            // 4 KB
    __shared__ int nstart[SKEYBINS];          // 4 KB
    __shared__ int cur[SKEYBINS];             // 4 KB
    __shared__ int wtot[8];

    const int g = blockIdx.x;
    const int tid = threadIdx.x;
    const int base = scanT[g * NCHUNK2];
    const int endE = scanT[(g + 1) * NCHUNK2];   // last group -> scanT[M]=E
    const int n = endE - base;
    const int crew = tid >> 3;                   // 0..63
    const int ql = tid & 7;
    const unsigned qlo = (unsigned)(ql << 4);
    const int nblk = gridDim.x;

    float4 accA[2], accB[2];      // node ni: dims ql*8+0..3 (A), +4..7 (B)
    #pragma unroll
    for (int ni = 0; ni < 2; ++ni) {
        accA[ni] = make_float4(0.f, 0.f, 0.f, 0.f);
        accB[ni] = make_float4(0.f, 0.f, 0.f, 0.f);
    }

    if (n <= TILE) {
        // ---- sort segment by (slice, node) ----
        const int NB = S * SPAN;
        for (int k = tid; k < NB; k += 512) hcnt[k] = 0;
        __syncthreads();
        for (int j = tid; j < n; j += 512) {
            uint2 r = stream8[base + j];
            int skey = (int)((r.x >> 15) >> SLICE_SH);
            atomicAdd(&hcnt[(skey << 7) + (int)r.y], 1);
        }
        __syncthreads();
        bin_scan(hcnt, nstart, cur, wtot, NB);
        for (int j = tid; j < n; j += 512) {        // L2-hot second read
            uint2 r = stream8[base + j];
            int skey = (int)((r.x >> 15) >> SLICE_SH);
            int slot = atomicAdd(&cur[(skey << 7) + (int)r.y], 1);
            srt[slot] = r.x;
        }
        __syncthreads();

        // ---- S phased walks, soft grid sync between ----
        for (int s = 0; s < S; ++s) {
            int k0 = nstart[(s << 7) + crew];
            int e0 = cur[(s << 7) + crew];
            int k1 = nstart[(s << 7) + crew + 64];
            int e1 = cur[(s << 7) + crew + 64];

            unsigned int pa0 = (k0 < e0) ? srt[k0] : 0u;
            unsigned int pb0 = (k1 < e1) ? srt[k1] : 0u;
            uint4 ra0 = rowld(emb16b, pa0, qlo);
            uint4 rb0 = rowld(emb16b, pb0, qlo);
            unsigned int pa1 = (k0 + 1 < e0) ? srt[k0 + 1] : 0u;
            unsigned int pb1 = (k1 + 1 < e1) ? srt[k1 + 1] : 0u;
            uint4 ra1 = rowld(emb16b, pa1, qlo);
            uint4 rb1 = rowld(emb16b, pb1, qlo);

            while ((k0 < e0) || (k1 < e1)) {
                unsigned int pa2 = (k0 + 2 < e0) ? srt[k0 + 2] : 0u;
                unsigned int pb2 = (k1 + 2 < e1) ? srt[k1 + 2] : 0u;
                uint4 ra2 = rowld(emb16b, pa2, qlo);
                uint4 rb2 = rowld(emb16b, pb2, qlo);
                if (k0 < e0)
                    fma8(accA[0], accB[0], ra0, h15_to_float(pa0 & 0x7FFFu));
                if (k1 < e1)
                    fma8(accA[1], accB[1], rb0, h15_to_float(pb0 & 0x7FFFu));
                pa0 = pa1; ra0 = ra1; pa1 = pa2; ra1 = ra2;
                pb0 = pb1; rb0 = rb1; pb1 = pb2; rb1 = rb2;
                ++k0; ++k1;
            }
            if (s < S - 1) soft_grid_sync(bar, s, nblk);
        }
    } else {
        // ---- overflow path (not expected at this shape): per-tile ----
        for (int tb = base; tb < endE; tb += TILE) {
            const int nt = min(TILE, endE - tb);
            if (tid < SPAN) hcnt[tid] = 0;
            __syncthreads();
            for (int j = tid; j < nt; j += 512)
                atomicAdd(&hcnt[(int)stream8[tb + j].y], 1);
            __syncthreads();
            bin_scan(hcnt, nstart, cur, wtot, SPAN);
            for (int j = tid; j < nt; j += 512) {
                uint2 r = stream8[tb + j];
                int slot = atomicAdd(&cur[(int)r.y], 1);
                srt[slot] = r.x;
            }
            __syncthreads();
            int k0 = nstart[crew];
            int e0 = cur[crew];
            int k1 = nstart[crew + 64];
            int e1 = cur[crew + 64];
            unsigned int pa0 = (k0 < e0) ? srt[k0] : 0u;
            unsigned int pb0 = (k1 < e1) ? srt[k1] : 0u;
            uint4 ra0 = rowld(emb16b, pa0, qlo);
            uint4 rb0 = rowld(emb16b, pb0, qlo);
            unsigned int pa1 = (k0 + 1 < e0) ? srt[k0 + 1] : 0u;
            unsigned int pb1 = (k1 + 1 < e1) ? srt[k1 + 1] : 0u;
            uint4 ra1 = rowld(emb16b, pa1, qlo);
            uint4 rb1 = rowld(emb16b, pb1, qlo);
            while ((k0 < e0) || (k1 < e1)) {
                unsigned int pa2 = (k0 + 2 < e0) ? srt[k0 + 2] : 0u;
                unsigned int pb2 = (k1 + 2 < e1) ? srt[k1 + 2] : 0u;
                uint4 ra2 = rowld(emb16b, pa2, qlo);
                uint4 rb2 = rowld(emb16b, pb2, qlo);
                if (k0 < e0)
                    fma8(accA[0], accB[0], ra0, h15_to_float(pa0 & 0x7FFFu));
                if (k1 < e1)
                    fma8(accA[1], accB[1], rb0, h15_to_float(pb0 & 0x7FFFu));
                pa0 = pa1; ra0 = ra1; pa1 = pa2; ra1 = ra2;
                pb0 = pb1; rb0 = rb1; pb1 = pb2; rb1 = rb2;
                ++k0; ++k1;
            }
            __syncthreads();
        }
        for (int s = 0; s < S - 1; ++s) soft_grid_sync(bar, s, nblk);
    }

    // ---- normalize + write (8-lane crew reduce) ----
    #pragma unroll
    for (int ni = 0; ni < 2; ++ni) {
        int node = g * SPAN + crew + (ni << 6);
        float4 aA = accA[ni];
        float4 aB = accB[ni];
        float ss = aA.x * aA.x + aA.y * aA.y + aA.z * aA.z + aA.w * aA.w
                 + aB.x * aB.x + aB.y * aB.y + aB.z * aB.z + aB.w * aB.w;
        ss += __shfl_xor(ss, 1, 64);
        ss += __shfl_xor(ss, 2, 64);
        ss += __shfl_xor(ss, 4, 64);
        float scale = 1.0f / fmaxf(sqrtf(ss), 1e-12f);
        if (node < N) {
            float4* po = reinterpret_cast<float4*>(out + (size_t)node * EMB_D
                                                   + (ql << 3));
            po[0] = make_float4(aA.x * scale, aA.y * scale,
                                aA.z * scale, aA.w * scale);
            po[1] = make_float4(aB.x * scale, aB.y * scale,
                                aB.z * scale, aB.w * scale);
        }
    }
}

// --- GF: unsliced fused gather (fallback for S > MAXS, proven R6) ---------
__global__ __launch_bounds__(512) void gather_fused(
        const char* __restrict__ emb16b,
        const uint2* __restrict__ stream8,
        const int* __restrict__ scanT,
        float* __restrict__ out, int N, int SN) {
    __shared__ uint2 lrec[TILE];
    __shared__ unsigned int srt[TILE];
    __shared__ int hcnt[SPAN];
    __shared__ int nstart[SPAN];
    __shared__ int cur[SPAN];
    __shared__ int wtot[2];

    const int g = blockIdx.x;
    const int tid = threadIdx.x;
    const int lane = tid & 63, wv = tid >> 6;
    const int base = scanT[(size_t)g * SN];
    const int endE = scanT[(size_t)(g + 1) * SN];
    const int crew = tid >> 4;
    const int ql = tid & 15;
    const int sub = ql >> 3;
    const int sl = ql & 7;
    const unsigned qlo = (unsigned)(sl << 4);

    float4 accA[4], accB[4];
    #pragma unroll
    for (int ni = 0; ni < 4; ++ni) {
        accA[ni] = make_float4(0.f, 0.f, 0.f, 0.f);
        accB[ni] = make_float4(0.f, 0.f, 0.f, 0.f);
    }

    for (int tb = base; tb < endE; tb += TILE) {
        const int n = min(TILE, endE - tb);
        if (tid < SPAN) hcnt[tid] = 0;
        __syncthreads();
        for (int j = tid; j < n; j += 512) {
            uint2 r = stream8[tb + j];
            lrec[j] = r;
            atomicAdd(&hcnt[r.y], 1);
        }
        __syncthreads();
        int v = (tid < SPAN) ? hcnt[tid] : 0;
        int x = v;
        #pragma unroll
        for (int off = 1; off < 64; off <<= 1) {
            int t = __shfl_up(x, off, 64);
            if (lane >= off) x += t;
        }
        if (wv < 2 && lane == 63) wtot[wv] = x;
        __syncthreads();
        if (tid < SPAN) {
            int excl = x - v + ((wv == 1) ? wtot[0] : 0);
            nstart[tid] = excl;
            cur[tid] = excl;
        }
        __syncthreads();
        for (int j = tid; j < n; j += 512) {
            uint2 r = lrec[j];
            int slot = atomicAdd(&cur[r.y], 1);
            srt[slot] = r.x;
        }
        __syncthreads();
        #pragma unroll
        for (int ni = 0; ni < 4; ++ni) {
            int nd = crew + (ni << 5);
            int s = nstart[nd];
            int e = cur[nd];
            float4 aA = accA[ni];
            float4 aB = accB[ni];
            int k0 = s + sub;
            unsigned int pk0 = (k0 < e) ? srt[k0] : 0u;
            uint4 r0 = rowld(emb16b, pk0, qlo);
            for (int k = k0; k < e; k += 2) {
                int k1 = k + 2;
                unsigned int pk1 = (k1 < e) ? srt[k1] : 0u;
                uint4 r1 = rowld(emb16b, pk1, qlo);
                fma8(aA, aB, r0, h15_to_float(pk0 & 0x7FFFu));
                pk0 = pk1; r0 = r1;
            }
            accA[ni] = aA;
            accB[ni] = aB;
        }
        __syncthreads();
    }

    #pragma unroll
    for (int ni = 0; ni < 4; ++ni) {
        accA[ni].x += __shfl_xor(accA[ni].x, 8, 64);
        accA[ni].y += __shfl_xor(accA[ni].y, 8, 64);
        accA[ni].z += __shfl_xor(accA[ni].z, 8, 64);
        accA[ni].w += __shfl_xor(accA[ni].w, 8, 64);
        accB[ni].x += __shfl_xor(accB[ni].x, 8, 64);
        accB[ni].y += __shfl_xor(accB[ni].y, 8, 64);
        accB[ni].z += __shfl_xor(accB[ni].z, 8, 64);
        accB[ni].w += __shfl_xor(accB[ni].w, 8, 64);
        int node = g * SPAN + crew + (ni << 5);
        float4 aA = accA[ni];
        float4 aB = accB[ni];
        float ss = aA.x * aA.x + aA.y * aA.y + aA.z * aA.z + aA.w * aA.w
                 + aB.x * aB.x + aB.y * aB.y + aB.z * aB.z + aB.w * aB.w;
        ss += __shfl_xor(ss, 1, 64);
        ss += __shfl_xor(ss, 2, 64);
        ss += __shfl_xor(ss, 4, 64);
        float scale = 1.0f / fmaxf(sqrtf(ss), 1e-12f);
        if (node < N) {
            float4 a = sub ? aB : aA;
            float4 o = make_float4(a.x * scale, a.y * scale,
                                   a.z * scale, a.w * scale);
            *reinterpret_cast<float4*>(out + (size_t)node * EMB_D
                                       + (sl << 3) + (sub << 2)) = o;
        }
    }
}

// ===========================================================================
// Tier C: atomic scatter fallback.
// ===========================================================================
__global__ void lightgcn_scatter(const float* __restrict__ emb,
                                 const float* __restrict__ w,
                                 const int* __restrict__ src,
                                 const int* __restrict__ dst,
                                 float* __restrict__ h, int E) {
    long long t = (long long)blockIdx.x * blockDim.x + threadIdx.x;
    int e = (int)(t >> 4);
    int d = (int)(t & 15) << 2;
    if (e >= E) return;
    int s = src[e]; int v = dst[e]; float wt = w[e];
    const float4 m = *reinterpret_cast<const float4*>(emb + (size_t)s * EMB_D + d);
    float* o = h + (size_t)v * EMB_D + d;
    unsafeAtomicAdd(o + 0, m.x * wt);
    unsafeAtomicAdd(o + 1, m.y * wt);
    unsafeAtomicAdd(o + 2, m.z * wt);
    unsafeAtomicAdd(o + 3, m.w * wt);
}

__global__ void lightgcn_normalize(float* __restrict__ h, int N) {
    int row = blockIdx.x * (blockDim.x >> 6) + (threadIdx.x >> 6);
    int lane = threadIdx.x & 63;
    if (row >= N) return;
    float x = h[(size_t)row * EMB_D + lane];
    float ss = x * x;
    #pragma unroll
    for (int off = 32; off > 0; off >>= 1)
        ss += __shfl_xor(ss, off, 64);
    h[(size_t)row * EMB_D + lane] = x / fmaxf(sqrtf(ss), 1e-12f);
}

extern "C" void kernel_launch(void* const* d_in, const int* in_sizes, int n_in,
                              void* d_out, int out_size, void* d_ws, size_t ws_size,
                              hipStream_t stream) {
    const float* emb = (const float*)d_in[0];   // [N, 64] fp32
    const float* w   = (const float*)d_in[1];   // [E] fp32
    const int*   src = (const int*)d_in[2];     // [E] int32
    const int*   dst = (const int*)d_in[3];     // [E] int32
    float* out = (float*)d_out;

    const int N = in_sizes[0] / EMB_D;
    const int E = in_sizes[1];
    const int block = 256;
    const int G = (N + SPAN - 1) / SPAN;
    const int S = (N + (1 << SLICE_SH) - 1) >> SLICE_SH;

    const int M3 = G * NCHUNK2;
    const int numB3 = (M3 + SB - 1) / SB;
    const int chunk3 = (E + NCHUNK2 - 1) / NCHUNK2;

    // ---- workspace: cntT[M3] | scanT[M3+1] | partial | blockoff | bar |
    //      pad | stream8[E] uint2 | pad | emb16 ----
    size_t intsA = (size_t)M3 + (size_t)(M3 + 1) + 2 * (size_t)numB3 + 1;
    size_t strOff = (intsA * sizeof(int) + 15) & ~(size_t)15;
    size_t embOff = (strOff + (size_t)E * sizeof(uint2) + 15) & ~(size_t)15;
    size_t needed = embOff + (size_t)N * EMB_D * sizeof(__half);

    if (ws_size >= needed && G <= MAXG && chunk3 <= CHMAX &&
        E < (1 << 28) && N < (1 << 17)) {
        int* cntT     = (int*)d_ws;              // M3
        int* scanT    = cntT + M3;               // M3+1
        int* partial  = scanT + M3 + 1;          // numB3
        int* blockoff = partial + numB3;         // numB3
        int* bar      = blockoff + numB3;        // 1
        uint2* stream8 = (uint2*)((char*)d_ws + strOff);   // E
        __half2* emb16 = (__half2*)((char*)d_ws + embOff);

        int n2 = N * (EMB_D / 2);

        hipMemsetAsync(bar, 0, sizeof(int), stream);

        a1_cast_hist<<<CAST_BLOCKS + NCHUNK2, block, 0, stream>>>(
            (const float2*)emb, emb16, n2, dst, cntT, E, G, chunk3);

        scan_reduceB<<<numB3, SB, 0, stream>>>(cntT, partial, M3);
        scan_partials<<<1, SB, 0, stream>>>(partial, blockoff, scanT, numB3, M3);
        scan_applyB<<<numB3, SB, 0, stream>>>(cntT, blockoff, scanT, M3);

        partition_sort<<<NCHUNK2, 512, 0, stream>>>(src, dst, w, cntT, scanT,
                                                    stream8, E, G, chunk3);

        if (S <= MAXS) {
            gather_sliced<<<G, 512, 0, stream>>>((const char*)emb16, stream8,
                                                 scanT, out, N, S, bar);
        } else {
            gather_fused<<<G, 512, 0, stream>>>((const char*)emb16, stream8,
                                                scanT, out, N, NCHUNK2);
        }
    } else {
        hipMemsetAsync(d_out, 0, (size_t)out_size * sizeof(float), stream);
        long long total = (long long)E * 16;
        int grid = (int)((total + block - 1) / block);
        lightgcn_scatter<<<grid, block, 0, stream>>>(emb, w, src, dst, out, E);
        int gridN = (N + 3) / 4;
        lightgcn_normalize<<<gridN, 256, 0, stream>>>(out, N);
    }
}

// Round 10
// 187.277 us; speedup vs baseline: 1.5071x; 1.5071x over previous
//
#include <hip/hip_runtime.h>
#include <hip/hip_fp16.h>

#define EMB_D 64
#define SB 1024     // scan block size
#define SPAN 64     // nodes per group (pow2: group = dst>>6, local = dst&63)
#define SPAN_SH 6
#define MAXG 2048   // max groups for LDS arrays
#define NCHUNK2 512 // edge chunks
#define CHMAX 4096  // max edges per chunk for LDS record buffer (32 KB)
#define TILE2 2048  // gather tile (records) -> srt 8 KB
#define CAST_BLOCKS 256

// ===========================================================================
// Tier A10: A6 structure, grid-limit fixed.
//   A1 : fused fp16 cast (float4 loads) + per-chunk group hist (LDS atomics)
//   scan: reduce + FUSED apply (each block self-computes blockoff from the
//         554-entry partial array; block 0 writes scanT[M]=E) -> 2 launches
//   PS : per-chunk LDS counting sort -> stream8 (group-contiguous)
//   GF : gather_fused64: SPAN=64 -> G=1107 blocks (4.3/CU, was 2.2 -> the
//        38% occupancy limiter). No lrec staging (stream8 re-read, L2-hot)
//        -> 9 KB LDS. Walk = R6's proven 16-lane crews, 2 substreams x
//        2-deep (16 rows in flight/wave) -- per-node lists unchanged.
// Tier C : atomic scatter fallback.
// R4: LDS-atomic accumulate ~100x too slow. R6: gather L2-miss-bound at
// ~147MB/3TB/s. R7-R9: slice phasing cuts FETCH to 43MB but shatters the
// walk (short lists = latency-bound); line abandoned. R9 insight: gather
// occupancy was GRID-limited (554 blocks) -> this kernel doubles G.
// ===========================================================================

__device__ __forceinline__ float h15_to_float(unsigned int bits) {
    return __half2float(__ushort_as_half((unsigned short)bits));
}

__device__ __forceinline__ uint4 rowld(const char* base, unsigned int pk,
                                       unsigned int qlo) {
    return *reinterpret_cast<const uint4*>(base + ((pk >> 15) * 128u + qlo));
}

__device__ __forceinline__ void fma8(float4& a, float4& b, uint4 r, float wt) {
    float2 x01 = __half22float2(*reinterpret_cast<__half2*>(&r.x));
    float2 x23 = __half22float2(*reinterpret_cast<__half2*>(&r.y));
    float2 x45 = __half22float2(*reinterpret_cast<__half2*>(&r.z));
    float2 x67 = __half22float2(*reinterpret_cast<__half2*>(&r.w));
    a.x = fmaf(x01.x, wt, a.x); a.y = fmaf(x01.y, wt, a.y);
    a.z = fmaf(x23.x, wt, a.z); a.w = fmaf(x23.y, wt, a.w);
    b.x = fmaf(x45.x, wt, b.x); b.y = fmaf(x45.y, wt, b.y);
    b.z = fmaf(x67.x, wt, b.z); b.w = fmaf(x67.y, wt, b.w);
}

// --- A1: fused cast (float4) + chunked group histogram --------------------
__global__ void a1_cast_hist(const float4* __restrict__ embin,
                             uint2* __restrict__ emb16, int n4,
                             const int* __restrict__ dst,
                             int* __restrict__ cntT,   // [G][NCHUNK2]
                             int E, int G, int chunk) {
    if (blockIdx.x < CAST_BLOCKS) {
        int i = blockIdx.x * blockDim.x + threadIdx.x;
        int st = CAST_BLOCKS * blockDim.x;
        for (; i < n4; i += st) {
            float4 v = embin[i];
            __half2 h0 = __float22half2_rn(make_float2(v.x, v.y));
            __half2 h1 = __float22half2_rn(make_float2(v.z, v.w));
            emb16[i] = make_uint2(*reinterpret_cast<unsigned int*>(&h0),
                                  *reinterpret_cast<unsigned int*>(&h1));
        }
    } else {
        __shared__ int bins[MAXG];
        int hb = blockIdx.x - CAST_BLOCKS;
        for (int g = threadIdx.x; g < G; g += blockDim.x) bins[g] = 0;
        __syncthreads();
        int beg = hb * chunk;
        int end = min(beg + chunk, E);
        for (int i = beg + threadIdx.x; i < end; i += blockDim.x)
            atomicAdd(&bins[dst[i] >> SPAN_SH], 1);
        __syncthreads();
        for (int g = threadIdx.x; g < G; g += blockDim.x)
            cntT[g * NCHUNK2 + hb] = bins[g];
    }
}

// --- scan: reduce (per-1024 partials) -------------------------------------
__global__ void scan_reduceB(const int* __restrict__ counts,
                             int* __restrict__ partial, int M) {
    __shared__ int wsum[16];
    const int tid = threadIdx.x, lane = tid & 63, wid = tid >> 6;
    int i = blockIdx.x * SB + tid;
    int v = (i < M) ? counts[i] : 0;
    #pragma unroll
    for (int off = 32; off > 0; off >>= 1)
        v += __shfl_xor(v, off, 64);
    if (lane == 0) wsum[wid] = v;
    __syncthreads();
    if (tid == 0) {
        int s = 0;
        #pragma unroll
        for (int k = 0; k < 16; ++k) s += wsum[k];
        partial[blockIdx.x] = s;
    }
}

// --- scan: fused apply (self-computed blockoff; block 0 writes total) -----
__global__ void scan_apply2(const int* __restrict__ counts,
                            const int* __restrict__ partial,
                            int* __restrict__ offsets, int M, int numB) {
    __shared__ int wsA[16];
    __shared__ int wsB[16];
    __shared__ int wsum[16];
    __shared__ int wpre[16];
    __shared__ int s_boff;
    const int tid = threadIdx.x, lane = tid & 63, wid = tid >> 6;
    const int bid = blockIdx.x;

    // block offset = sum(partial[0..bid)); total = sum(partial[0..numB))
    int pall = (tid < numB) ? partial[tid] : 0;
    int ppre = (tid < bid) ? pall : 0;
    int sa = pall, sb = ppre;
    #pragma unroll
    for (int off = 32; off > 0; off >>= 1) {
        sa += __shfl_xor(sa, off, 64);
        sb += __shfl_xor(sb, off, 64);
    }
    if (lane == 0) { wsA[wid] = sa; wsB[wid] = sb; }
    __syncthreads();
    if (tid == 0) {
        int a = 0, b = 0;
        #pragma unroll
        for (int k = 0; k < 16; ++k) { a += wsA[k]; b += wsB[k]; }
        s_boff = b;
        if (bid == 0) offsets[M] = a;   // grand total = E
    }
    __syncthreads();
    const int boff = s_boff;

    // standard in-block exclusive scan of counts
    int i = bid * SB + tid;
    int v = (i < M) ? counts[i] : 0;
    int x = v;
    #pragma unroll
    for (int off = 1; off < 64; off <<= 1) {
        int t = __shfl_up(x, off, 64);
        if (lane >= off) x += t;
    }
    if (lane == 63) wsum[wid] = x;
    __syncthreads();
    if (wid == 0) {
        int s = (lane < 16) ? wsum[lane] : 0;
        #pragma unroll
        for (int off = 1; off < 16; off <<= 1) {
            int t = __shfl_up(s, off, 64);
            if (lane >= off) s += t;
        }
        if (lane < 16) wpre[lane] = s;
    }
    __syncthreads();
    int excl = boff + ((wid > 0) ? wpre[wid - 1] : 0) + (x - v);
    if (i < M) offsets[i] = excl;
}

// --- PS: per-chunk LDS counting sort + linear coalesced drain (512 thr) ---
__global__ __launch_bounds__(512) void partition_sort(
        const int* __restrict__ src,
        const int* __restrict__ dst,
        const float* __restrict__ w,
        const int* __restrict__ cntT,    // [G][NCHUNK2]
        const int* __restrict__ scanT,   // [G*NCHUNK2+1]
        uint2* __restrict__ stream8,     // [E]
        int E, int G, int chunk) {
    __shared__ uint2 recs[CHMAX];        // 32 KB
    __shared__ int cur[MAXG];            // 8 KB
    __shared__ int delta[MAXG];          // 8 KB
    __shared__ int wtot[8];

    const int tid = threadIdx.x, lane = tid & 63, wv = tid >> 6;
    const int b = blockIdx.x;
    const int beg = b * chunk;
    const int end = min(beg + chunk, E);
    const int n = end - beg;

    const int K = (G + 511) >> 9;        // <= 4 (G <= MAXG)
    int vals[4];
    int acc = 0;
    #pragma unroll
    for (int k = 0; k < 4; ++k) {
        int g = tid * K + k;
        int c = (k < K && g < G) ? cntT[g * NCHUNK2 + b] : 0;
        vals[k] = c;
        acc += c;
    }
    int x = acc;
    #pragma unroll
    for (int off = 1; off < 64; off <<= 1) {
        int t = __shfl_up(x, off, 64);
        if (lane >= off) x += t;
    }
    if (lane == 63) wtot[wv] = x;
    __syncthreads();
    int woff = 0;
    #pragma unroll
    for (int k2 = 0; k2 < 8; ++k2)
        woff += (k2 < wv) ? wtot[k2] : 0;
    int run = woff + x - acc;            // exclusive prefix (local base)
    #pragma unroll
    for (int k = 0; k < 4; ++k) {
        int g = tid * K + k;
        if (k < K && g < G) {
            cur[g] = run;
            delta[g] = scanT[g * NCHUNK2 + b] - run;
            run += vals[k];
        }
    }
    __syncthreads();

    for (int i = beg + tid; i < end; i += 512) {
        int d = dst[i];
        unsigned int wb = __half_as_ushort(__float2half_rn(w[i]));
        unsigned int pk = ((unsigned int)src[i] << 15) | (wb & 0x7FFFu);
        int g = d >> SPAN_SH;
        int j = atomicAdd(&cur[g], 1);
        recs[j] = make_uint2(pk, (unsigned int)(d & (SPAN - 1)) |
                                 ((unsigned int)g << SPAN_SH));
    }
    __syncthreads();

    for (int j = tid; j < n; j += 512) {
        uint2 r = recs[j];
        int g = (int)(r.y >> SPAN_SH);
        stream8[delta[g] + j] = make_uint2(r.x, r.y & (SPAN - 1u));
    }
}

// --- GF64: fused per-group CSR + register gather + normalize (SPAN=64) ----
// Crew = 16 lanes owns nodes {c, c+32}; two 8-lane substreams per node,
// uint4 rows, 2-deep each -> 16 rows in flight per wave (R6-proven walk).
// No lrec: stream8 segment read twice (2nd read L2-hot). LDS ~9 KB.
__global__ __launch_bounds__(512) void gather_fused64(
        const char* __restrict__ emb16b,      // row v at byte v*128
        const uint2* __restrict__ stream8,    // [E] {pk, dl}
        const int* __restrict__ scanT,        // [G*NCHUNK2+1]
        float* __restrict__ out, int N) {
    __shared__ unsigned int srt[TILE2];       // 8 KB
    __shared__ int hcnt[SPAN];
    __shared__ int nstart[SPAN];
    __shared__ int cur[SPAN];

    const int g = blockIdx.x;
    const int tid = threadIdx.x;
    const int base = scanT[g * NCHUNK2];
    const int endE = scanT[(g + 1) * NCHUNK2];   // last group -> scanT[M]=E
    const int crew = tid >> 4;                   // 0..31
    const int ql = tid & 15;
    const int sub = ql >> 3;                     // substream 0/1
    const int sl = ql & 7;                       // 16B segment of row
    const unsigned qlo = (unsigned)(sl << 4);

    float4 accA[2], accB[2];                  // node ni: dims sl*8+0..3/+4..7
    #pragma unroll
    for (int ni = 0; ni < 2; ++ni) {
        accA[ni] = make_float4(0.f, 0.f, 0.f, 0.f);
        accB[ni] = make_float4(0.f, 0.f, 0.f, 0.f);
    }

    for (int tb = base; tb < endE; tb += TILE2) {
        const int n = min(TILE2, endE - tb);
        if (tid < SPAN) hcnt[tid] = 0;
        __syncthreads();
        // pass 1: node histogram
        for (int j = tid; j < n; j += 512)
            atomicAdd(&hcnt[(int)stream8[tb + j].y], 1);
        __syncthreads();
        // exclusive scan of 64 counters (wave 0)
        if (tid < SPAN) {
            int v = hcnt[tid];
            int x = v;
            #pragma unroll
            for (int off = 1; off < 64; off <<= 1) {
                int t = __shfl_up(x, off, 64);
                if (tid >= off) x += t;
            }
            nstart[tid] = x - v;
            cur[tid] = x - v;
        }
        __syncthreads();
        // pass 2: node-sorted place (stream8 re-read, L2-hot)
        for (int j = tid; j < n; j += 512) {
            uint2 r = stream8[tb + j];
            int slot = atomicAdd(&cur[(int)r.y], 1);
            srt[slot] = r.x;
        }
        __syncthreads();
        // gather: crew walks its 2 nodes, 2 substreams each, 2-deep
        #pragma unroll
        for (int ni = 0; ni < 2; ++ni) {
            int nd = crew + (ni << 5);
            int s = nstart[nd];
            int e = cur[nd];
            float4 aA = accA[ni];
            float4 aB = accB[ni];
            int k0 = s + sub;
            unsigned int pk0 = (k0 < e) ? srt[k0] : 0u;
            uint4 r0 = rowld(emb16b, pk0, qlo);
            for (int k = k0; k < e; k += 2) {
                int k1 = k + 2;
                unsigned int pk1 = (k1 < e) ? srt[k1] : 0u;
                uint4 r1 = rowld(emb16b, pk1, qlo);   // next in flight
                fma8(aA, aB, r0, h15_to_float(pk0 & 0x7FFFu));
                pk0 = pk1; r0 = r1;
            }
            accA[ni] = aA;
            accB[ni] = aB;
        }
        __syncthreads();
    }

    // merge substreams, normalize, write
    #pragma unroll
    for (int ni = 0; ni < 2; ++ni) {
        accA[ni].x += __shfl_xor(accA[ni].x, 8, 64);
        accA[ni].y += __shfl_xor(accA[ni].y, 8, 64);
        accA[ni].z += __shfl_xor(accA[ni].z, 8, 64);
        accA[ni].w += __shfl_xor(accA[ni].w, 8, 64);
        accB[ni].x += __shfl_xor(accB[ni].x, 8, 64);
        accB[ni].y += __shfl_xor(accB[ni].y, 8, 64);
        accB[ni].z += __shfl_xor(accB[ni].z, 8, 64);
        accB[ni].w += __shfl_xor(accB[ni].w, 8, 64);
        int node = g * SPAN + crew + (ni << 5);
        float4 aA = accA[ni];
        float4 aB = accB[ni];
        float ss = aA.x * aA.x + aA.y * aA.y + aA.z * aA.z + aA.w * aA.w
                 + aB.x * aB.x + aB.y * aB.y + aB.z * aB.z + aB.w * aB.w;
        ss += __shfl_xor(ss, 1, 64);
        ss += __shfl_xor(ss, 2, 64);
        ss += __shfl_xor(ss, 4, 64);
        float scale = 1.0f / fmaxf(sqrtf(ss), 1e-12f);
        if (node < N) {
            float4 a = sub ? aB : aA;
            float4 o = make_float4(a.x * scale, a.y * scale,
                                   a.z * scale, a.w * scale);
            *reinterpret_cast<float4*>(out + (size_t)node * EMB_D
                                       + (sl << 3) + (sub << 2)) = o;
        }
    }
}

// ===========================================================================
// Tier C: atomic scatter fallback.
// ===========================================================================
__global__ void lightgcn_scatter(const float* __restrict__ emb,
                                 const float* __restrict__ w,
                                 const int* __restrict__ src,
                                 const int* __restrict__ dst,
                                 float* __restrict__ h, int E) {
    long long t = (long long)blockIdx.x * blockDim.x + threadIdx.x;
    int e = (int)(t >> 4);
    int d = (int)(t & 15) << 2;
    if (e >= E) return;
    int s = src[e]; int v = dst[e]; float wt = w[e];
    const float4 m = *reinterpret_cast<const float4*>(emb + (size_t)s * EMB_D + d);
    float* o = h + (size_t)v * EMB_D + d;
    unsafeAtomicAdd(o + 0, m.x * wt);
    unsafeAtomicAdd(o + 1, m.y * wt);
    unsafeAtomicAdd(o + 2, m.z * wt);
    unsafeAtomicAdd(o + 3, m.w * wt);
}

__global__ void lightgcn_normalize(float* __restrict__ h, int N) {
    int row = blockIdx.x * (blockDim.x >> 6) + (threadIdx.x >> 6);
    int lane = threadIdx.x & 63;
    if (row >= N) return;
    float x = h[(size_t)row * EMB_D + lane];
    float ss = x * x;
    #pragma unroll
    for (int off = 32; off > 0; off >>= 1)
        ss += __shfl_xor(ss, off, 64);
    h[(size_t)row * EMB_D + lane] = x / fmaxf(sqrtf(ss), 1e-12f);
}

extern "C" void kernel_launch(void* const* d_in, const int* in_sizes, int n_in,
                              void* d_out, int out_size, void* d_ws, size_t ws_size,
                              hipStream_t stream) {
    const float* emb = (const float*)d_in[0];   // [N, 64] fp32
    const float* w   = (const float*)d_in[1];   // [E] fp32
    const int*   src = (const int*)d_in[2];     // [E] int32
    const int*   dst = (const int*)d_in[3];     // [E] int32
    float* out = (float*)d_out;

    const int N = in_sizes[0] / EMB_D;
    const int E = in_sizes[1];
    const int block = 256;
    const int G = (N + SPAN - 1) / SPAN;

    const int M3 = G * NCHUNK2;
    const int numB3 = (M3 + SB - 1) / SB;
    const int chunk3 = (E + NCHUNK2 - 1) / NCHUNK2;

    // ---- workspace: cntT[M3] | scanT[M3+1] | partial[numB3] | pad |
    //      stream8[E] uint2 | pad | emb16  (~30 MB) ----
    size_t intsA = (size_t)M3 + (size_t)(M3 + 1) + (size_t)numB3;
    size_t strOff = (intsA * sizeof(int) + 15) & ~(size_t)15;
    size_t embOff = (strOff + (size_t)E * sizeof(uint2) + 15) & ~(size_t)15;
    size_t needed = embOff + (size_t)N * EMB_D * sizeof(__half);

    if (ws_size >= needed && G <= MAXG && chunk3 <= CHMAX && numB3 <= SB &&
        E < (1 << 28) && N < (1 << 17)) {
        int* cntT     = (int*)d_ws;              // M3
        int* scanT    = cntT + M3;               // M3+1
        int* partial  = scanT + M3 + 1;          // numB3
        uint2* stream8 = (uint2*)((char*)d_ws + strOff);   // E
        uint2* emb16 = (uint2*)((char*)d_ws + embOff);

        int n4 = N * (EMB_D / 4);

        a1_cast_hist<<<CAST_BLOCKS + NCHUNK2, block, 0, stream>>>(
            (const float4*)emb, emb16, n4, dst, cntT, E, G, chunk3);

        scan_reduceB<<<numB3, SB, 0, stream>>>(cntT, partial, M3);
        scan_apply2<<<numB3, SB, 0, stream>>>(cntT, partial, scanT, M3, numB3);

        partition_sort<<<NCHUNK2, 512, 0, stream>>>(src, dst, w, cntT, scanT,
                                                    stream8, E, G, chunk3);

        gather_fused64<<<G, 512, 0, stream>>>((const char*)emb16, stream8,
                                              scanT, out, N);
    } else {
        hipMemsetAsync(d_out, 0, (size_t)out_size * sizeof(float), stream);
        long long total = (long long)E * 16;
        int grid = (int)((total + block - 1) / block);
        lightgcn_scatter<<<grid, block, 0, stream>>>(emb, w, src, dst, out, E);
        int gridN = (N + 3) / 4;
        lightgcn_normalize<<<gridN, 256, 0, stream>>>(out, N);
    }
}

// Round 12
// 182.502 us; speedup vs baseline: 1.5465x; 1.0262x over previous
//
#include <hip/hip_runtime.h>
#include <hip/hip_fp16.h>

#define EMB_D 64
#define SB 1024      // scan block size
#define SPAN 128     // nodes per group (group = dst>>7, local = dst&127)
#define SPAN_SH 7
#define MAXG 1024    // max groups for LDS arrays
#define NCHUNK2 512  // edge chunks for partition
#define CHMAX 4096   // max edges per chunk (32 KB recs)
#define TILE 4096    // gather tile (records)
#define CAST_BLOCKS 256
#define HIST_BLOCKS 128

// ===========================================================================
// Tier A11: atomic-reservation front-end (5 dispatches), R6 gather.
//   F1 : fused fp16 cast (float4) + 554-bin GLOBAL histogram
//        (per-block LDS hist -> <=70K global atomicAdds). No count matrix.
//   F2 : one block scans G bins -> offsets[G+1] + cursors[G].
//   F3 : partition: per-chunk LDS counting sort (as R6); per-(block,group)
//        base via ONE atomicAdd(&cursors[g], cnt) -- order within a group
//        segment is arrival-order (gather re-sorts per tile, sum-order
//        only). XCD-contiguous chunk remap: consecutive chunks (adjacent
//        runs of the same segment) on the same XCD -> write combining.
//   GF : gather_fused = R6's proven kernel (lrec-staged, 16-lane crews,
//        2 substreams x 2-deep = 16 rows in flight/wave), offsets bounds.
// Tier C : atomic scatter fallback.
// Ledger: R4 LDS-atomic accum ~100x slow. R6 gather local-opt 55us,
// L2-miss-bound 147MB@3TB/s. R7-R9 slice phasing: FETCH 43MB but walk
// shattered; abandoned. R10: gather occupancy NOT the limiter; psort drain
// is write-combining-bound (run length matters). R11: front-end was
// 120us for ~85MB traffic -> kill matrix+scans, XCD-align the drain.
// R11 bench attempt failed on container acquire (infra); resubmission.
// ===========================================================================

__device__ __forceinline__ float h15_to_float(unsigned int bits) {
    return __half2float(__ushort_as_half((unsigned short)bits));
}

__device__ __forceinline__ uint4 rowld(const char* base, unsigned int pk,
                                       unsigned int qlo) {
    return *reinterpret_cast<const uint4*>(base + ((pk >> 15) * 128u + qlo));
}

__device__ __forceinline__ void fma8(float4& a, float4& b, uint4 r, float wt) {
    float2 x01 = __half22float2(*reinterpret_cast<__half2*>(&r.x));
    float2 x23 = __half22float2(*reinterpret_cast<__half2*>(&r.y));
    float2 x45 = __half22float2(*reinterpret_cast<__half2*>(&r.z));
    float2 x67 = __half22float2(*reinterpret_cast<__half2*>(&r.w));
    a.x = fmaf(x01.x, wt, a.x); a.y = fmaf(x01.y, wt, a.y);
    a.z = fmaf(x23.x, wt, a.z); a.w = fmaf(x23.y, wt, a.w);
    b.x = fmaf(x45.x, wt, b.x); b.y = fmaf(x45.y, wt, b.y);
    b.z = fmaf(x67.x, wt, b.z); b.w = fmaf(x67.y, wt, b.w);
}

// --- F1: fused cast (float4) + global group histogram ---------------------
__global__ void f1_cast_hist(const float4* __restrict__ embin,
                             uint2* __restrict__ emb16, int n4,
                             const int* __restrict__ dst,
                             int* __restrict__ hist,   // [G], pre-zeroed
                             int E, int G, int hchunk) {
    if (blockIdx.x < CAST_BLOCKS) {
        int i = blockIdx.x * blockDim.x + threadIdx.x;
        int st = CAST_BLOCKS * blockDim.x;
        for (; i < n4; i += st) {
            float4 v = embin[i];
            __half2 h0 = __float22half2_rn(make_float2(v.x, v.y));
            __half2 h1 = __float22half2_rn(make_float2(v.z, v.w));
            emb16[i] = make_uint2(*reinterpret_cast<unsigned int*>(&h0),
                                  *reinterpret_cast<unsigned int*>(&h1));
        }
    } else {
        __shared__ int bins[MAXG];
        int hb = blockIdx.x - CAST_BLOCKS;
        for (int g = threadIdx.x; g < G; g += blockDim.x) bins[g] = 0;
        __syncthreads();
        int beg = hb * hchunk;
        int end = min(beg + hchunk, E);
        for (int i = beg + threadIdx.x; i < end; i += blockDim.x)
            atomicAdd(&bins[dst[i] >> SPAN_SH], 1);
        __syncthreads();
        for (int g = threadIdx.x; g < G; g += blockDim.x)
            if (bins[g]) atomicAdd(&hist[g], bins[g]);
    }
}

// --- F2: single-block exclusive scan of G (<=1024) bins -------------------
__global__ void f2_scan_small(const int* __restrict__ hist,
                              int* __restrict__ offsets,
                              int* __restrict__ cursors, int G) {
    __shared__ int wsum[16];
    __shared__ int wpre[16];
    const int tid = threadIdx.x, lane = tid & 63, wid = tid >> 6;
    int v = (tid < G) ? hist[tid] : 0;
    int x = v;
    #pragma unroll
    for (int off = 1; off < 64; off <<= 1) {
        int t = __shfl_up(x, off, 64);
        if (lane >= off) x += t;
    }
    if (lane == 63) wsum[wid] = x;
    __syncthreads();
    if (wid == 0) {
        int s = (lane < 16) ? wsum[lane] : 0;
        #pragma unroll
        for (int off = 1; off < 16; off <<= 1) {
            int t = __shfl_up(s, off, 64);
            if (lane >= off) s += t;
        }
        if (lane < 16) wpre[lane] = s;
    }
    __syncthreads();
    int excl = ((wid > 0) ? wpre[wid - 1] : 0) + (x - v);
    if (tid < G) { offsets[tid] = excl; cursors[tid] = excl; }
    if (tid == 0) offsets[G] = wpre[15];   // grand total = E
}

// --- F3: partition with atomic reservation + XCD-contiguous chunks --------
__global__ __launch_bounds__(512) void partition_atomic(
        const int* __restrict__ src,
        const int* __restrict__ dst,
        const float* __restrict__ w,
        int* __restrict__ cursors,       // [G] init = offsets[g]
        uint2* __restrict__ stream8,     // [E]
        int E, int G, int chunk) {
    __shared__ uint2 recs[CHMAX];        // 32 KB
    __shared__ int cur[MAXG];            // 4 KB
    __shared__ int delta[MAXG];          // 4 KB
    __shared__ int wtot[8];

    const int tid = threadIdx.x, lane = tid & 63, wv = tid >> 6;
    // XCD-contiguous remap: block b (XCD b%8) takes chunk (b%8)*64 + b/8,
    // so chunks c and c+1 (adjacent output runs) are on the SAME XCD.
    const int b = blockIdx.x;
    const int c = (b & 7) * (NCHUNK2 >> 3) + (b >> 3);
    const int beg = c * chunk;
    const int end = min(beg + chunk, E);
    const int n = end - beg;

    // phase 1: local histogram
    for (int g = tid; g < G; g += 512) cur[g] = 0;
    __syncthreads();
    for (int i = beg + tid; i < end; i += 512)
        atomicAdd(&cur[dst[i] >> SPAN_SH], 1);
    __syncthreads();

    // phase 2: in-block scan -> local starts; atomic global reservation
    const int K = (G + 511) >> 9;        // <= 2 (G <= MAXG)
    int vals[2];
    int acc = 0;
    #pragma unroll
    for (int k = 0; k < 2; ++k) {
        int g = tid * K + k;
        int cc = (k < K && g < G) ? cur[g] : 0;
        vals[k] = cc;
        acc += cc;
    }
    int x = acc;
    #pragma unroll
    for (int off = 1; off < 64; off <<= 1) {
        int t = __shfl_up(x, off, 64);
        if (lane >= off) x += t;
    }
    if (lane == 63) wtot[wv] = x;
    __syncthreads();
    int woff = 0;
    #pragma unroll
    for (int k2 = 0; k2 < 8; ++k2)
        woff += (k2 < wv) ? wtot[k2] : 0;
    int run = woff + x - acc;            // exclusive local start
    #pragma unroll
    for (int k = 0; k < 2; ++k) {
        int g = tid * K + k;
        if (k < K && g < G) {
            int cc = vals[k];
            cur[g] = run;                // own entries only: no race
            if (cc > 0)
                delta[g] = atomicAdd(&cursors[g], cc) - run;
            run += cc;
        }
    }
    __syncthreads();

    // phase 3: LDS scatter, group-sorted (chunk edges L1/L2-hot re-read)
    for (int i = beg + tid; i < end; i += 512) {
        int d = dst[i];
        unsigned int wb = __half_as_ushort(__float2half_rn(w[i]));
        unsigned int pk = ((unsigned int)src[i] << 15) | (wb & 0x7FFFu);
        int g = d >> SPAN_SH;
        int j = atomicAdd(&cur[g], 1);
        recs[j] = make_uint2(pk, (unsigned int)(d & (SPAN - 1)) |
                                 ((unsigned int)g << SPAN_SH));
    }
    __syncthreads();

    // phase 4: linear coalesced drain
    for (int j = tid; j < n; j += 512) {
        uint2 r = recs[j];
        int g = (int)(r.y >> SPAN_SH);
        stream8[delta[g] + j] = make_uint2(r.x, r.y & (SPAN - 1u));
    }
}

// --- GF: fused per-group CSR + register gather + normalize (R6 proven) ----
// Crew = 16 lanes owns nodes {c, c+32, c+64, c+96}; two 8-lane substreams,
// uint4 rows, 2-deep each -> 16 rows in flight per wave.
__global__ __launch_bounds__(512) void gather_fused(
        const char* __restrict__ emb16b,      // row v at byte v*128
        const uint2* __restrict__ stream8,    // [E] {pk, dl}
        const int* __restrict__ offsets,      // [G+1]
        float* __restrict__ out, int N) {
    __shared__ uint2 lrec[TILE];              // 32 KB
    __shared__ unsigned int srt[TILE];        // 16 KB
    __shared__ int hcnt[SPAN];
    __shared__ int nstart[SPAN];
    __shared__ int cur[SPAN];
    __shared__ int wtot[2];

    const int g = blockIdx.x;
    const int tid = threadIdx.x;
    const int lane = tid & 63, wv = tid >> 6;
    const int base = offsets[g];
    const int endE = offsets[g + 1];
    const int crew = tid >> 4;                   // 0..31
    const int ql = tid & 15;
    const int sub = ql >> 3;                     // substream 0/1
    const int sl = ql & 7;                       // 16B segment of row
    const unsigned qlo = (unsigned)(sl << 4);

    float4 accA[4], accB[4];                  // dims sl*8+0..3 / +4..7
    #pragma unroll
    for (int ni = 0; ni < 4; ++ni) {
        accA[ni] = make_float4(0.f, 0.f, 0.f, 0.f);
        accB[ni] = make_float4(0.f, 0.f, 0.f, 0.f);
    }

    for (int tb = base; tb < endE; tb += TILE) {
        const int n = min(TILE, endE - tb);
        if (tid < SPAN) hcnt[tid] = 0;
        __syncthreads();
        for (int j = tid; j < n; j += 512) {
            uint2 r = stream8[tb + j];
            lrec[j] = r;
            atomicAdd(&hcnt[r.y], 1);
        }
        __syncthreads();
        int v = (tid < SPAN) ? hcnt[tid] : 0;
        int x = v;
        #pragma unroll
        for (int off = 1; off < 64; off <<= 1) {
            int t = __shfl_up(x, off, 64);
            if (lane >= off) x += t;
        }
        if (wv < 2 && lane == 63) wtot[wv] = x;
        __syncthreads();
        if (tid < SPAN) {
            int excl = x - v + ((wv == 1) ? wtot[0] : 0);
            nstart[tid] = excl;
            cur[tid] = excl;
        }
        __syncthreads();
        for (int j = tid; j < n; j += 512) {
            uint2 r = lrec[j];
            int slot = atomicAdd(&cur[r.y], 1);
            srt[slot] = r.x;
        }
        __syncthreads();
        #pragma unroll
        for (int ni = 0; ni < 4; ++ni) {
            int nd = crew + (ni << 5);
            int s = nstart[nd];
            int e = cur[nd];
            float4 aA = accA[ni];
            float4 aB = accB[ni];
            int k0 = s + sub;
            unsigned int pk0 = (k0 < e) ? srt[k0] : 0u;
            uint4 r0 = rowld(emb16b, pk0, qlo);
            for (int k = k0; k < e; k += 2) {
                int k1 = k + 2;
                unsigned int pk1 = (k1 < e) ? srt[k1] : 0u;
                uint4 r1 = rowld(emb16b, pk1, qlo);   // next in flight
                fma8(aA, aB, r0, h15_to_float(pk0 & 0x7FFFu));
                pk0 = pk1; r0 = r1;
            }
            accA[ni] = aA;
            accB[ni] = aB;
        }
        __syncthreads();
    }

    // merge substreams, normalize, write
    #pragma unroll
    for (int ni = 0; ni < 4; ++ni) {
        accA[ni].x += __shfl_xor(accA[ni].x, 8, 64);
        accA[ni].y += __shfl_xor(accA[ni].y, 8, 64);
        accA[ni].z += __shfl_xor(accA[ni].z, 8, 64);
        accA[ni].w += __shfl_xor(accA[ni].w, 8, 64);
        accB[ni].x += __shfl_xor(accB[ni].x, 8, 64);
        accB[ni].y += __shfl_xor(accB[ni].y, 8, 64);
        accB[ni].z += __shfl_xor(accB[ni].z, 8, 64);
        accB[ni].w += __shfl_xor(accB[ni].w, 8, 64);
        int node = g * SPAN + crew + (ni << 5);
        float4 aA = accA[ni];
        float4 aB = accB[ni];
        float ss = aA.x * aA.x + aA.y * aA.y + aA.z * aA.z + aA.w * aA.w
                 + aB.x * aB.x + aB.y * aB.y + aB.z * aB.z + aB.w * aB.w;
        ss += __shfl_xor(ss, 1, 64);
        ss += __shfl_xor(ss, 2, 64);
        ss += __shfl_xor(ss, 4, 64);
        float scale = 1.0f / fmaxf(sqrtf(ss), 1e-12f);
        if (node < N) {
            float4 a = sub ? aB : aA;
            float4 o = make_float4(a.x * scale, a.y * scale,
                                   a.z * scale, a.w * scale);
            *reinterpret_cast<float4*>(out + (size_t)node * EMB_D
                                       + (sl << 3) + (sub << 2)) = o;
        }
    }
}

// ===========================================================================
// Tier C: atomic scatter fallback.
// ===========================================================================
__global__ void lightgcn_scatter(const float* __restrict__ emb,
                                 const float* __restrict__ w,
                                 const int* __restrict__ src,
                                 const int* __restrict__ dst,
                                 float* __restrict__ h, int E) {
    long long t = (long long)blockIdx.x * blockDim.x + threadIdx.x;
    int e = (int)(t >> 4);
    int d = (int)(t & 15) << 2;
    if (e >= E) return;
    int s = src[e]; int v = dst[e]; float wt = w[e];
    const float4 m = *reinterpret_cast<const float4*>(emb + (size_t)s * EMB_D + d);
    float* o = h + (size_t)v * EMB_D + d;
    unsafeAtomicAdd(o + 0, m.x * wt);
    unsafeAtomicAdd(o + 1, m.y * wt);
    unsafeAtomicAdd(o + 2, m.z * wt);
    unsafeAtomicAdd(o + 3, m.w * wt);
}

__global__ void lightgcn_normalize(float* __restrict__ h, int N) {
    int row = blockIdx.x * (blockDim.x >> 6) + (threadIdx.x >> 6);
    int lane = threadIdx.x & 63;
    if (row >= N) return;
    float x = h[(size_t)row * EMB_D + lane];
    float ss = x * x;
    #pragma unroll
    for (int off = 32; off > 0; off >>= 1)
        ss += __shfl_xor(ss, off, 64);
    h[(size_t)row * EMB_D + lane] = x / fmaxf(sqrtf(ss), 1e-12f);
}

extern "C" void kernel_launch(void* const* d_in, const int* in_sizes, int n_in,
                              void* d_out, int out_size, void* d_ws, size_t ws_size,
                              hipStream_t stream) {
    const float* emb = (const float*)d_in[0];   // [N, 64] fp32
    const float* w   = (const float*)d_in[1];   // [E] fp32
    const int*   src = (const int*)d_in[2];     // [E] int32
    const int*   dst = (const int*)d_in[3];     // [E] int32
    float* out = (float*)d_out;

    const int N = in_sizes[0] / EMB_D;
    const int E = in_sizes[1];
    const int block = 256;
    const int G = (N + SPAN - 1) / SPAN;
    const int chunk = (E + NCHUNK2 - 1) / NCHUNK2;
    const int hchunk = (E + HIST_BLOCKS - 1) / HIST_BLOCKS;

    // ---- workspace: hist[G] | offsets[G+1] | cursors[G] | pad |
    //      stream8[E] uint2 | pad | emb16  (~25.1 MB) ----
    size_t ints = 3 * (size_t)G + 1;
    size_t strOff = (ints * sizeof(int) + 15) & ~(size_t)15;
    size_t embOff = (strOff + (size_t)E * sizeof(uint2) + 15) & ~(size_t)15;
    size_t needed = embOff + (size_t)N * EMB_D * sizeof(__half);

    if (ws_size >= needed && G <= MAXG && chunk <= CHMAX &&
        E < (1 << 28) && N < (1 << 17)) {
        int* hist    = (int*)d_ws;               // G
        int* offsets = hist + G;                 // G+1
        int* cursors = offsets + G + 1;          // G
        uint2* stream8 = (uint2*)((char*)d_ws + strOff);   // E
        uint2* emb16 = (uint2*)((char*)d_ws + embOff);

        int n4 = N * (EMB_D / 4);

        hipMemsetAsync(hist, 0, (size_t)G * sizeof(int), stream);

        f1_cast_hist<<<CAST_BLOCKS + HIST_BLOCKS, block, 0, stream>>>(
            (const float4*)emb, emb16, n4, dst, hist, E, G, hchunk);

        f2_scan_small<<<1, SB, 0, stream>>>(hist, offsets, cursors, G);

        partition_atomic<<<NCHUNK2, 512, 0, stream>>>(src, dst, w, cursors,
                                                      stream8, E, G, chunk);

        gather_fused<<<G, 512, 0, stream>>>((const char*)emb16, stream8,
                                            offsets, out, N);
    } else {
        hipMemsetAsync(d_out, 0, (size_t)out_size * sizeof(float), stream);
        long long total = (long long)E * 16;
        int grid = (int)((total + block - 1) / block);
        lightgcn_scatter<<<grid, block, 0, stream>>>(emb, w, src, dst, out, E);
        int gridN = (N + 3) / 4;
        lightgcn_normalize<<<gridN, 256, 0, stream>>>(out, N);
    }
}

// Round 13
// 175.577 us; speedup vs baseline: 1.6075x; 1.0394x over previous
//
#include <hip/hip_runtime.h>
#include <hip/hip_fp16.h>

#define EMB_D 64
#define SPAN 128     // nodes per group (group = dst>>7, local = dst&127)
#define SPAN_SH 7
#define MAXG 1024    // max groups for LDS arrays
#define NCHUNK2 512  // edge chunks for partition
#define CHMAX 4096   // max edges per chunk (32 KB recs)
#define TILE 4096    // gather tile (records)
#define CAST_BLOCKS 256

// ===========================================================================
// Tier A13: hybrid front-end — cnt matrix (R6) + atomic reservation (R12).
//   A1 : fused fp16 cast (float4) + per-chunk group hist -> cntT[G][512]
//        (ONE dst pass; partition never re-histograms).
//   RS : rowsum: G blocks sum cntT rows -> hist[G]  (~2 us).
//   SC : one block scans G bins -> offsets[G+1] + cursors[G]  (~1 us).
//   PR : partition_res: R6's LDS counting sort; local counts from cntT,
//        global base via ONE atomicAdd(&cursors[g], cnt) (no 567K scan).
//        XCD-contiguous chunk remap for drain write-combining.
//   GF : gather_fused = R6's proven kernel (lrec, 16-lane crews,
//        2 substreams x 2-deep = 16 rows/wave in flight).
// Tier C : atomic scatter fallback.
// Ledger: R4 LDS-atomic accum ~100x slow. R6 gather local-opt ~50-55us,
// L2-miss-bound 147MB@~3.3TB/s (R7-R9 slice phasing cut FETCH to 43MB but
// shattered the walk -> abandoned). R10 occupancy not gather's limiter;
// drain is write-combining-bound. R12: arrival-order stream OK (gather
// re-sorts); cursor atomics OK; but partition's own hist pass cost more
// than the scans it replaced -> this round removes that pass.
// ===========================================================================

__device__ __forceinline__ float h15_to_float(unsigned int bits) {
    return __half2float(__ushort_as_half((unsigned short)bits));
}

__device__ __forceinline__ uint4 rowld(const char* base, unsigned int pk,
                                       unsigned int qlo) {
    return *reinterpret_cast<const uint4*>(base + ((pk >> 15) * 128u + qlo));
}

__device__ __forceinline__ void fma8(float4& a, float4& b, uint4 r, float wt) {
    float2 x01 = __half22float2(*reinterpret_cast<__half2*>(&r.x));
    float2 x23 = __half22float2(*reinterpret_cast<__half2*>(&r.y));
    float2 x45 = __half22float2(*reinterpret_cast<__half2*>(&r.z));
    float2 x67 = __half22float2(*reinterpret_cast<__half2*>(&r.w));
    a.x = fmaf(x01.x, wt, a.x); a.y = fmaf(x01.y, wt, a.y);
    a.z = fmaf(x23.x, wt, a.z); a.w = fmaf(x23.y, wt, a.w);
    b.x = fmaf(x45.x, wt, b.x); b.y = fmaf(x45.y, wt, b.y);
    b.z = fmaf(x67.x, wt, b.z); b.w = fmaf(x67.y, wt, b.w);
}

// --- A1: fused cast (float4) + per-chunk group histogram ------------------
__global__ void a1_cast_hist(const float4* __restrict__ embin,
                             uint2* __restrict__ emb16, int n4,
                             const int* __restrict__ dst,
                             int* __restrict__ cntT,   // [G][NCHUNK2]
                             int E, int G, int chunk) {
    if (blockIdx.x < CAST_BLOCKS) {
        int i = blockIdx.x * blockDim.x + threadIdx.x;
        int st = CAST_BLOCKS * blockDim.x;
        for (; i < n4; i += st) {
            float4 v = embin[i];
            __half2 h0 = __float22half2_rn(make_float2(v.x, v.y));
            __half2 h1 = __float22half2_rn(make_float2(v.z, v.w));
            emb16[i] = make_uint2(*reinterpret_cast<unsigned int*>(&h0),
                                  *reinterpret_cast<unsigned int*>(&h1));
        }
    } else {
        __shared__ int bins[MAXG];
        int hb = blockIdx.x - CAST_BLOCKS;
        for (int g = threadIdx.x; g < G; g += blockDim.x) bins[g] = 0;
        __syncthreads();
        int beg = hb * chunk;
        int end = min(beg + chunk, E);
        for (int i = beg + threadIdx.x; i < end; i += blockDim.x)
            atomicAdd(&bins[dst[i] >> SPAN_SH], 1);
        __syncthreads();
        for (int g = threadIdx.x; g < G; g += blockDim.x)
            cntT[g * NCHUNK2 + hb] = bins[g];
    }
}

// --- RS: per-group row sum of cntT -> hist --------------------------------
__global__ void rowsum_kernel(const int* __restrict__ cntT,
                              int* __restrict__ hist, int G) {
    __shared__ int wsum[4];
    const int g = blockIdx.x;
    const int tid = threadIdx.x, lane = tid & 63, wid = tid >> 6;
    int s = cntT[g * NCHUNK2 + tid] + cntT[g * NCHUNK2 + tid + 256];
    #pragma unroll
    for (int off = 32; off > 0; off >>= 1)
        s += __shfl_xor(s, off, 64);
    if (lane == 0) wsum[wid] = s;
    __syncthreads();
    if (tid == 0)
        hist[g] = wsum[0] + wsum[1] + wsum[2] + wsum[3];
}

// --- SC: single-block exclusive scan of G (<=1024) bins -------------------
__global__ void f2_scan_small(const int* __restrict__ hist,
                              int* __restrict__ offsets,
                              int* __restrict__ cursors, int G) {
    __shared__ int wsum[16];
    __shared__ int wpre[16];
    const int tid = threadIdx.x, lane = tid & 63, wid = tid >> 6;
    int v = (tid < G) ? hist[tid] : 0;
    int x = v;
    #pragma unroll
    for (int off = 1; off < 64; off <<= 1) {
        int t = __shfl_up(x, off, 64);
        if (lane >= off) x += t;
    }
    if (lane == 63) wsum[wid] = x;
    __syncthreads();
    if (wid == 0) {
        int s = (lane < 16) ? wsum[lane] : 0;
        #pragma unroll
        for (int off = 1; off < 16; off <<= 1) {
            int t = __shfl_up(s, off, 64);
            if (lane >= off) s += t;
        }
        if (lane < 16) wpre[lane] = s;
    }
    __syncthreads();
    int excl = ((wid > 0) ? wpre[wid - 1] : 0) + (x - v);
    if (tid < G) { offsets[tid] = excl; cursors[tid] = excl; }
    if (tid == 0) offsets[G] = wpre[15];   // grand total = E
}

// --- PR: partition with cntT counts + atomic reservation ------------------
__global__ __launch_bounds__(512) void partition_res(
        const int* __restrict__ src,
        const int* __restrict__ dst,
        const float* __restrict__ w,
        const int* __restrict__ cntT,    // [G][NCHUNK2]
        int* __restrict__ cursors,       // [G] init = offsets[g]
        uint2* __restrict__ stream8,     // [E]
        int E, int G, int chunk) {
    __shared__ uint2 recs[CHMAX];        // 32 KB
    __shared__ int cur[MAXG];            // 4 KB
    __shared__ int delta[MAXG];          // 4 KB
    __shared__ int wtot[8];

    const int tid = threadIdx.x, lane = tid & 63, wv = tid >> 6;
    // XCD-contiguous remap: block b (XCD b%8) takes chunk (b%8)*64 + b/8,
    // so adjacent output runs land on the SAME XCD (write combining).
    const int b = blockIdx.x;
    const int c = (b & 7) * (NCHUNK2 >> 3) + (b >> 3);
    const int beg = c * chunk;
    const int end = min(beg + chunk, E);
    const int n = end - beg;

    // local counts from cntT; in-block scan -> local starts; atomic base
    const int K = (G + 511) >> 9;        // <= 2 (G <= MAXG)
    int vals[2];
    int acc = 0;
    #pragma unroll
    for (int k = 0; k < 2; ++k) {
        int g = tid * K + k;
        int cc = (k < K && g < G) ? cntT[g * NCHUNK2 + c] : 0;
        vals[k] = cc;
        acc += cc;
    }
    int x = acc;
    #pragma unroll
    for (int off = 1; off < 64; off <<= 1) {
        int t = __shfl_up(x, off, 64);
        if (lane >= off) x += t;
    }
    if (lane == 63) wtot[wv] = x;
    __syncthreads();
    int woff = 0;
    #pragma unroll
    for (int k2 = 0; k2 < 8; ++k2)
        woff += (k2 < wv) ? wtot[k2] : 0;
    int run = woff + x - acc;            // exclusive local start
    #pragma unroll
    for (int k = 0; k < 2; ++k) {
        int g = tid * K + k;
        if (k < K && g < G) {
            int cc = vals[k];
            cur[g] = run;                // own entries only: no race
            if (cc > 0)
                delta[g] = atomicAdd(&cursors[g], cc) - run;
            run += cc;
        }
    }
    __syncthreads();

    // LDS scatter, group-sorted (single dst/src/w pass)
    for (int i = beg + tid; i < end; i += 512) {
        int d = dst[i];
        unsigned int wb = __half_as_ushort(__float2half_rn(w[i]));
        unsigned int pk = ((unsigned int)src[i] << 15) | (wb & 0x7FFFu);
        int g = d >> SPAN_SH;
        int j = atomicAdd(&cur[g], 1);
        recs[j] = make_uint2(pk, (unsigned int)(d & (SPAN - 1)) |
                                 ((unsigned int)g << SPAN_SH));
    }
    __syncthreads();

    // linear coalesced drain
    for (int j = tid; j < n; j += 512) {
        uint2 r = recs[j];
        int g = (int)(r.y >> SPAN_SH);
        stream8[delta[g] + j] = make_uint2(r.x, r.y & (SPAN - 1u));
    }
}

// --- GF: fused per-group CSR + register gather + normalize (R6 proven) ----
__global__ __launch_bounds__(512) void gather_fused(
        const char* __restrict__ emb16b,      // row v at byte v*128
        const uint2* __restrict__ stream8,    // [E] {pk, dl}
        const int* __restrict__ offsets,      // [G+1]
        float* __restrict__ out, int N) {
    __shared__ uint2 lrec[TILE];              // 32 KB
    __shared__ unsigned int srt[TILE];        // 16 KB
    __shared__ int hcnt[SPAN];
    __shared__ int nstart[SPAN];
    __shared__ int cur[SPAN];
    __shared__ int wtot[2];

    const int g = blockIdx.x;
    const int tid = threadIdx.x;
    const int lane = tid & 63, wv = tid >> 6;
    const int base = offsets[g];
    const int endE = offsets[g + 1];
    const int crew = tid >> 4;                   // 0..31
    const int ql = tid & 15;
    const int sub = ql >> 3;                     // substream 0/1
    const int sl = ql & 7;                       // 16B segment of row
    const unsigned qlo = (unsigned)(sl << 4);

    float4 accA[4], accB[4];                  // dims sl*8+0..3 / +4..7
    #pragma unroll
    for (int ni = 0; ni < 4; ++ni) {
        accA[ni] = make_float4(0.f, 0.f, 0.f, 0.f);
        accB[ni] = make_float4(0.f, 0.f, 0.f, 0.f);
    }

    for (int tb = base; tb < endE; tb += TILE) {
        const int n = min(TILE, endE - tb);
        if (tid < SPAN) hcnt[tid] = 0;
        __syncthreads();
        for (int j = tid; j < n; j += 512) {
            uint2 r = stream8[tb + j];
            lrec[j] = r;
            atomicAdd(&hcnt[r.y], 1);
        }
        __syncthreads();
        int v = (tid < SPAN) ? hcnt[tid] : 0;
        int x = v;
        #pragma unroll
        for (int off = 1; off < 64; off <<= 1) {
            int t = __shfl_up(x, off, 64);
            if (lane >= off) x += t;
        }
        if (wv < 2 && lane == 63) wtot[wv] = x;
        __syncthreads();
        if (tid < SPAN) {
            int excl = x - v + ((wv == 1) ? wtot[0] : 0);
            nstart[tid] = excl;
            cur[tid] = excl;
        }
        __syncthreads();
        for (int j = tid; j < n; j += 512) {
            uint2 r = lrec[j];
            int slot = atomicAdd(&cur[r.y], 1);
            srt[slot] = r.x;
        }
        __syncthreads();
        #pragma unroll
        for (int ni = 0; ni < 4; ++ni) {
            int nd = crew + (ni << 5);
            int s = nstart[nd];
            int e = cur[nd];
            float4 aA = accA[ni];
            float4 aB = accB[ni];
            int k0 = s + sub;
            unsigned int pk0 = (k0 < e) ? srt[k0] : 0u;
            uint4 r0 = rowld(emb16b, pk0, qlo);
            for (int k = k0; k < e; k += 2) {
                int k1 = k + 2;
                unsigned int pk1 = (k1 < e) ? srt[k1] : 0u;
                uint4 r1 = rowld(emb16b, pk1, qlo);   // next in flight
                fma8(aA, aB, r0, h15_to_float(pk0 & 0x7FFFu));
                pk0 = pk1; r0 = r1;
            }
            accA[ni] = aA;
            accB[ni] = aB;
        }
        __syncthreads();
    }

    // merge substreams, normalize, write
    #pragma unroll
    for (int ni = 0; ni < 4; ++ni) {
        accA[ni].x += __shfl_xor(accA[ni].x, 8, 64);
        accA[ni].y += __shfl_xor(accA[ni].y, 8, 64);
        accA[ni].z += __shfl_xor(accA[ni].z, 8, 64);
        accA[ni].w += __shfl_xor(accA[ni].w, 8, 64);
        accB[ni].x += __shfl_xor(accB[ni].x, 8, 64);
        accB[ni].y += __shfl_xor(accB[ni].y, 8, 64);
        accB[ni].z += __shfl_xor(accB[ni].z, 8, 64);
        accB[ni].w += __shfl_xor(accB[ni].w, 8, 64);
        int node = g * SPAN + crew + (ni << 5);
        float4 aA = accA[ni];
        float4 aB = accB[ni];
        float ss = aA.x * aA.x + aA.y * aA.y + aA.z * aA.z + aA.w * aA.w
                 + aB.x * aB.x + aB.y * aB.y + aB.z * aB.z + aB.w * aB.w;
        ss += __shfl_xor(ss, 1, 64);
        ss += __shfl_xor(ss, 2, 64);
        ss += __shfl_xor(ss, 4, 64);
        float scale = 1.0f / fmaxf(sqrtf(ss), 1e-12f);
        if (node < N) {
            float4 a = sub ? aB : aA;
            float4 o = make_float4(a.x * scale, a.y * scale,
                                   a.z * scale, a.w * scale);
            *reinterpret_cast<float4*>(out + (size_t)node * EMB_D
                                       + (sl << 3) + (sub << 2)) = o;
        }
    }
}

// ===========================================================================
// Tier C: atomic scatter fallback.
// ===========================================================================
__global__ void lightgcn_scatter(const float* __restrict__ emb,
                                 const float* __restrict__ w,
                                 const int* __restrict__ src,
                                 const int* __restrict__ dst,
                                 float* __restrict__ h, int E) {
    long long t = (long long)blockIdx.x * blockDim.x + threadIdx.x;
    int e = (int)(t >> 4);
    int d = (int)(t & 15) << 2;
    if (e >= E) return;
    int s = src[e]; int v = dst[e]; float wt = w[e];
    const float4 m = *reinterpret_cast<const float4*>(emb + (size_t)s * EMB_D + d);
    float* o = h + (size_t)v * EMB_D + d;
    unsafeAtomicAdd(o + 0, m.x * wt);
    unsafeAtomicAdd(o + 1, m.y * wt);
    unsafeAtomicAdd(o + 2, m.z * wt);
    unsafeAtomicAdd(o + 3, m.w * wt);
}

__global__ void lightgcn_normalize(float* __restrict__ h, int N) {
    int row = blockIdx.x * (blockDim.x >> 6) + (threadIdx.x >> 6);
    int lane = threadIdx.x & 63;
    if (row >= N) return;
    float x = h[(size_t)row * EMB_D + lane];
    float ss = x * x;
    #pragma unroll
    for (int off = 32; off > 0; off >>= 1)
        ss += __shfl_xor(ss, off, 64);
    h[(size_t)row * EMB_D + lane] = x / fmaxf(sqrtf(ss), 1e-12f);
}

extern "C" void kernel_launch(void* const* d_in, const int* in_sizes, int n_in,
                              void* d_out, int out_size, void* d_ws, size_t ws_size,
                              hipStream_t stream) {
    const float* emb = (const float*)d_in[0];   // [N, 64] fp32
    const float* w   = (const float*)d_in[1];   // [E] fp32
    const int*   src = (const int*)d_in[2];     // [E] int32
    const int*   dst = (const int*)d_in[3];     // [E] int32
    float* out = (float*)d_out;

    const int N = in_sizes[0] / EMB_D;
    const int E = in_sizes[1];
    const int block = 256;
    const int G = (N + SPAN - 1) / SPAN;
    const int chunk = (E + NCHUNK2 - 1) / NCHUNK2;

    // ---- workspace: cntT[G*NCHUNK2] | hist[G] | offsets[G+1] | cursors[G]
    //      | pad | stream8[E] uint2 | pad | emb16  (~26.3 MB) ----
    size_t ints = (size_t)G * NCHUNK2 + 3 * (size_t)G + 1;
    size_t strOff = (ints * sizeof(int) + 15) & ~(size_t)15;
    size_t embOff = (strOff + (size_t)E * sizeof(uint2) + 15) & ~(size_t)15;
    size_t needed = embOff + (size_t)N * EMB_D * sizeof(__half);

    if (ws_size >= needed && G <= MAXG && chunk <= CHMAX &&
        E < (1 << 28) && N < (1 << 17)) {
        int* cntT    = (int*)d_ws;               // G*NCHUNK2
        int* hist    = cntT + (size_t)G * NCHUNK2;  // G
        int* offsets = hist + G;                 // G+1
        int* cursors = offsets + G + 1;          // G
        uint2* stream8 = (uint2*)((char*)d_ws + strOff);   // E
        uint2* emb16 = (uint2*)((char*)d_ws + embOff);

        int n4 = N * (EMB_D / 4);

        a1_cast_hist<<<CAST_BLOCKS + NCHUNK2, block, 0, stream>>>(
            (const float4*)emb, emb16, n4, dst, cntT, E, G, chunk);

        rowsum_kernel<<<G, 256, 0, stream>>>(cntT, hist, G);
        f2_scan_small<<<1, 1024, 0, stream>>>(hist, offsets, cursors, G);

        partition_res<<<NCHUNK2, 512, 0, stream>>>(src, dst, w, cntT, cursors,
                                                   stream8, E, G, chunk);

        gather_fused<<<G, 512, 0, stream>>>((const char*)emb16, stream8,
                                            offsets, out, N);
    } else {
        hipMemsetAsync(d_out, 0, (size_t)out_size * sizeof(float), stream);
        long long total = (long long)E * 16;
        int grid = (int)((total + block - 1) / block);
        lightgcn_scatter<<<grid, block, 0, stream>>>(emb, w, src, dst, out, E);
        int gridN = (N + 3) / 4;
        lightgcn_normalize<<<gridN, 256, 0, stream>>>(out, N);
    }
}